// Round 3
// baseline (453.965 us; speedup 1.0000x reference)
//
#include <hip/hip_runtime.h>
#include <hip/hip_bf16.h>

// Problem constants (fixed by reference setup_inputs)
constexpr int NN   = 50000;    // nodes
constexpr int NE   = 600000;   // edges
constexpr int NRBF = 50;       // rbf features
constexpr int DIM  = 128;      // embedding dim
constexpr float CUT = 5.0f;
constexpr float PI_F = 3.14159265358979323846f;

constexpr int CAP = 32;        // bucket capacity (active degree ~Poisson(10); P(>32)~1e-9, ovf fallback)

// Workspace layout (byte offsets). Total 34.6 MB.
constexpr size_t OFF_DEG   = 0;                                // [NN] int
constexpr size_t OFF_OVFC  = (size_t)NN * 4;                   // [1] int (memset covers both)
constexpr size_t OFF_EID   = 200960;                           // [NN*CAP] int   (6.4 MB)
constexpr size_t OFF_CCB   = OFF_EID  + (size_t)NN * CAP * 4;  // [NN*CAP] float (6.4 MB)
constexpr size_t OFF_TAUB  = OFF_CCB  + (size_t)NN * CAP * 4;  // [NN*CAP] int   (6.4 MB)
constexpr size_t OFF_OVF   = OFF_TAUB + (size_t)NN * CAP * 4;  // [NE] int       (2.4 MB)
constexpr size_t OFF_WAUG  = OFF_OVF  + (size_t)NE * 4;        // [128*64] bf16 (16 KB)
constexpr size_t OFF_EPERM = OFF_WAUG + 128 * 64 * 2;          // [100*128] bf16 permuted (25.6 KB)
constexpr size_t OFF_XI    = OFF_EPERM + 100 * 128 * 2;        // [NN*128] bf16 normal order (12.8 MB)

// emb_perm PERMUTED layout: position p holds dim delta(p) = 16*(p&7) + (p>>3).
// Lane c's positions 8c..8c+7 <-> dims {16q + c} = exactly its MFMA-D column across nt.

typedef __attribute__((ext_vector_type(4))) float f32x4;
typedef __attribute__((ext_vector_type(8))) short short8;

__device__ __forceinline__ float bf2f(unsigned short u) {
    return __uint_as_float(((unsigned int)u) << 16);
}
__device__ __forceinline__ unsigned short f2bf(float f) {
    return __bfloat16_as_ushort(__float2bfloat16(f));
}

// ---------------------------------------------------------------------------
// Kernel 0: prep small weights — W_aug[d][64] = [W_e[d][0..49] | b_e[d] | 0...],
// emb_perm[tau][p] = emb[tau][delta(p)], both bf16.
// ---------------------------------------------------------------------------
__global__ __launch_bounds__(256)
void prep_w(const float* __restrict__ W_e, const float* __restrict__ b_e,
            const float* __restrict__ emb,
            unsigned short* __restrict__ W_aug, unsigned short* __restrict__ emb_perm)
{
    const int tid = blockIdx.x * 256 + threadIdx.x;
    if (tid < 128 * 64) {
        const int d = tid >> 6, k = tid & 63;
        float v = 0.0f;
        if (k < NRBF)       v = W_e[d * NRBF + k];
        else if (k == NRBF) v = b_e[d];
        W_aug[tid] = f2bf(v);
    } else if (tid < 128 * 64 + 100 * 128) {
        const int i = tid - 128 * 64;
        const int tau = i >> 7, p = i & 127;
        const int d = 16 * (p & 7) + (p >> 3);
        emb_perm[i] = f2bf(emb[tau * DIM + d]);
    }
}

// ---------------------------------------------------------------------------
// Kernel 1: bucket active edges by dst. Bucket slot carries (eid, cc, tau).
// ---------------------------------------------------------------------------
__global__ __launch_bounds__(256)
void build_buckets(const int* __restrict__ dst, const float* __restrict__ dist,
                   const int* __restrict__ src, const int* __restrict__ node_type,
                   int* __restrict__ deg, int* __restrict__ eid,
                   float* __restrict__ ccb, int* __restrict__ taub,
                   int* __restrict__ ovf, int* __restrict__ ovf_cnt)
{
    const int e = blockIdx.x * 256 + threadIdx.x;
    if (e >= NE) return;
    const float dd = dist[e];
    if (dd >= CUT) return;                       // inactive: contributes nothing
    const float w = 0.5f * (__cosf(dd * (PI_F / CUT)) + 1.0f);
    const int n = dst[e];
    const int pos = atomicAdd(&deg[n], 1);
    if (pos < CAP) {
        eid[n * CAP + pos]  = e;
        ccb[n * CAP + pos]  = w;
        taub[n * CAP + pos] = node_type[src[e]];
    } else {
        ovf[atomicAdd(ovf_cnt, 1)] = e;
    }
}

// ---------------------------------------------------------------------------
// Kernel 2 (FUSED edge_msg + gather_sum): one wave per node.
//
// R2 post-mortem: the shfl-based variant FAILED correctness (absmax 0.758).
// Hand-simulation of the intended dataflow matches R0's proven semantics, so
// the repair removes the two unproven mechanisms:
//   (a) ALL cross-lane __shfl of bucket data is replaced by direct per-lane
//       global loads (eid/ccb/taub[n*CAP+slot]) — the epilogue shfl read
//       exec-inactive source lanes under a divergent guard (UB per HIP).
//       The addresses are one 128-B line per array per node: free via L1.
//   (b) the numeric path is bit-matched to R0: each per-edge product is
//       rounded through bf16 (bf2f(f2bf(acc*m))) before f32 accumulation —
//       identical term set and roundings as msg-materialize + gather-sum,
//       only the f32 summation order differs.
//
// Per round of 16 edges (slots j0..j0+15):
//   A-frag: lane (c,g) owns slot j0+c, k-chunk 8g..8g+7 (a0) and 32+8g (a1),
//           cc folded into A, k50 = cc (b_e hook). Rows >= degn zeroed.
//   B-frag: W_aug rows (register-resident, L2-hot 16 KB).
//   D:      lane (c,g) acc[nt][r] = dim 16nt+c of slot j0+4g+r.
//   Epilogue: v[8] += bf16(acc * emb_perm[tau]) per owned row.
// After all rounds: butterfly over g, store xi normal order. No LDS/barriers.
// ---------------------------------------------------------------------------
__global__ __launch_bounds__(256)
void gather_fused(const float* __restrict__ rbf,
                  const int* __restrict__ deg, const int* __restrict__ eid,
                  const float* __restrict__ ccb, const int* __restrict__ taub,
                  const unsigned short* __restrict__ W_aug,
                  const unsigned short* __restrict__ emb_perm,
                  const int* __restrict__ ovf, const int* __restrict__ ovf_cnt,
                  const int* __restrict__ dst, const float* __restrict__ dist,
                  const int* __restrict__ src, const int* __restrict__ node_type,
                  unsigned short* __restrict__ xi)
{
    const int t = threadIdx.x, l = t & 63;
    const int c = l & 15, g = l >> 4;
    const int n = blockIdx.x * 4 + (t >> 6);
    if (n >= NN) return;

    // B fragments: row nt*16+c of W_aug, k-chunk [s*32+g*8 .. +7]. 16 KB, L2-hot.
    short8 bfrag[16];
    #pragma unroll
    for (int nt = 0; nt < 8; ++nt)
        #pragma unroll
        for (int s = 0; s < 2; ++s)
            bfrag[nt * 2 + s] =
                *(const short8*)(W_aug + (nt * 16 + c) * 64 + s * 32 + g * 8);

    const int dn   = deg[n];
    const int degn = dn < CAP ? dn : CAP;
    const int base = n * CAP;

    float v[8] = {};

    for (int j0 = 0; j0 < degn; j0 += 16) {
        // This lane's A row: bucket slot j0+c, loaded DIRECTLY (no shfl).
        const int slot = j0 + c;
        int   ea  = 0;
        float ccl = 0.0f;
        if (slot < degn) {
            ea  = eid[base + slot];
            ccl = ccb[base + slot];
        }
        const float* rp = rbf + (size_t)ea * NRBF;        // ea=0 when inactive: safe

        const float2* rp2 = (const float2*)rp;
        const float2 r0 = rp2[4 * g];
        const float2 r1 = rp2[4 * g + 1];
        const float2 r2 = rp2[4 * g + 2];
        const float2 r3 = rp2[4 * g + 3];
        float2 q0 = make_float2(0.f, 0.f), q1 = q0, q2 = q0, q3 = q0;
        if (g < 2) {
            q0 = rp2[16 + 4 * g];
            q1 = rp2[17 + 4 * g];
            q2 = rp2[18 + 4 * g];
            q3 = rp2[19 + 4 * g];
        } else if (g == 2) {
            q0 = rp2[24];                                 // k48,k49
        }

        short8 a0, a1;
        a0[0] = (short)f2bf(ccl * r0.x); a0[1] = (short)f2bf(ccl * r0.y);
        a0[2] = (short)f2bf(ccl * r1.x); a0[3] = (short)f2bf(ccl * r1.y);
        a0[4] = (short)f2bf(ccl * r2.x); a0[5] = (short)f2bf(ccl * r2.y);
        a0[6] = (short)f2bf(ccl * r3.x); a0[7] = (short)f2bf(ccl * r3.y);
        a1[0] = (short)f2bf(ccl * q0.x); a1[1] = (short)f2bf(ccl * q0.y);
        a1[2] = (short)f2bf(ccl * q1.x); a1[3] = (short)f2bf(ccl * q1.y);
        a1[4] = (short)f2bf(ccl * q2.x); a1[5] = (short)f2bf(ccl * q2.y);
        a1[6] = (short)f2bf(ccl * q3.x); a1[7] = (short)f2bf(ccl * q3.y);
        if (g == 2) {                                     // k50 = cc (b_e hook), k51+ = 0
            a1[2] = (short)f2bf(ccl);
            a1[3] = 0; a1[4] = 0; a1[5] = 0; a1[6] = 0; a1[7] = 0;
        }

        f32x4 acc[8] = {};
        #pragma unroll
        for (int nt = 0; nt < 8; ++nt)
            acc[nt] = __builtin_amdgcn_mfma_f32_16x16x32_bf16(a0, bfrag[nt * 2],
                                                              acc[nt], 0, 0, 0);
        #pragma unroll
        for (int nt = 0; nt < 8; ++nt)
            acc[nt] = __builtin_amdgcn_mfma_f32_16x16x32_bf16(a1, bfrag[nt * 2 + 1],
                                                              acc[nt], 0, 0, 0);

        // Accumulate: lane (c,g) owns dims 16nt+c of slots j0+4g+r.
        // tau loaded directly per row (address uniform across the 16 c-lanes).
        #pragma unroll
        for (int r = 0; r < 4; ++r) {
            const int jr = j0 + 4 * g + r;
            if (jr < degn) {
                const int rw = taub[base + jr];
                const int4 em = *(const int4*)(emb_perm + rw * DIM + 8 * c);
                const unsigned int* ep = (const unsigned int*)&em;
                #pragma unroll
                for (int q = 0; q < 4; ++q) {
                    const float m0 = bf2f((unsigned short)(ep[q] & 0xffff));
                    const float m1 = bf2f((unsigned short)(ep[q] >> 16));
                    // bf16-round each product: bit-identical to R0's msg path.
                    v[2 * q]     += bf2f(f2bf(acc[2 * q][r]     * m0));
                    v[2 * q + 1] += bf2f(f2bf(acc[2 * q + 1][r] * m1));
                }
            }
        }
    }

    // Overflow fallback (deg > CAP): essentially never taken, kept for correctness.
    // Scalar recompute of the edge message, g==0 lanes only (butterfly counts once).
    const int ocnt = ovf_cnt[0];
    for (int j = 0; j < ocnt; ++j) {
        const int e = ovf[j];
        if (dst[e] != n) continue;
        const float dd  = dist[e];
        const float ccl = 0.5f * (__cosf(dd * (PI_F / CUT)) + 1.0f);  // ovf edges are active
        if (g == 0) {
            const int tau = node_type[src[e]];
            const float* rp = rbf + (size_t)e * NRBF;
            const float ccb16 = bf2f(f2bf(ccl));
            #pragma unroll
            for (int q = 0; q < 8; ++q) {
                const int d = 16 * q + c;
                float s = bf2f(W_aug[d * 64 + NRBF]) * ccb16;         // b_e * cc (k50 hook)
                for (int k = 0; k < NRBF; ++k)
                    s += bf2f(W_aug[d * 64 + k]) * bf2f(f2bf(ccl * rp[k]));
                v[q] += bf2f(f2bf(s * bf2f(emb_perm[tau * DIM + 8 * c + q])));
            }
        }
    }

    #pragma unroll
    for (int q = 0; q < 8; ++q) {
        v[q] += __shfl_xor(v[q], 16);
        v[q] += __shfl_xor(v[q], 32);
    }

    // lane (c,g) holds dims {16q+c}; store dims 32g+c (=v[2g]) and 32g+16+c (=v[2g+1]).
    float s0 = v[0], s1 = v[1];
    if (g == 1)      { s0 = v[2]; s1 = v[3]; }
    else if (g == 2) { s0 = v[4]; s1 = v[5]; }
    else if (g == 3) { s0 = v[6]; s1 = v[7]; }
    xi[(size_t)n * DIM + 32 * g + c]      = f2bf(s0);
    xi[(size_t)n * DIM + 32 * g + 16 + c] = f2bf(s1);
}

// ---------------------------------------------------------------------------
// Kernel 3: out[n] = [x_nodes[n] | xi[n]] @ W_c^T + b_c  via bf16 MFMA.
// (unchanged — known good)
// ---------------------------------------------------------------------------
__global__ __launch_bounds__(256)
void combine_mfma(const float* __restrict__ x_nodes, const __hip_bfloat16* __restrict__ xi,
                  const float* __restrict__ W_c, const float* __restrict__ b_c,
                  float* __restrict__ out)
{
    __shared__ unsigned short As[64][72];
    __shared__ unsigned short Bs[128][72];

    const int t  = threadIdx.x;
    const int wv = t >> 6;
    const int l  = t & 63;
    const int n0 = blockIdx.x * 64;

    f32x4 acc[8] = {};

    for (int kc = 0; kc < 4; ++kc) {
        const int kb = kc * 64;
        if (kc) __syncthreads();
        {
            const int r  = t >> 2;
            const int c0 = (t & 3) * 16;
            const int n  = n0 + r;
            if (kc < 2) {
                float4 v[4];
                if (n < NN) {
                    const float4* p = (const float4*)(x_nodes + (size_t)n * DIM + kb + c0);
                    v[0] = p[0]; v[1] = p[1]; v[2] = p[2]; v[3] = p[3];
                } else {
                    v[0] = v[1] = v[2] = v[3] = make_float4(0.f, 0.f, 0.f, 0.f);
                }
                unsigned short* dp = &As[r][c0];
                #pragma unroll
                for (int q = 0; q < 4; ++q) {
                    *(ushort2*)&dp[q * 4]     = make_ushort2(f2bf(v[q].x), f2bf(v[q].y));
                    *(ushort2*)&dp[q * 4 + 2] = make_ushort2(f2bf(v[q].z), f2bf(v[q].w));
                }
            } else {
                int4 v0 = make_int4(0, 0, 0, 0), v1 = make_int4(0, 0, 0, 0);
                if (n < NN) {
                    const int4* p = (const int4*)(xi + (size_t)n * DIM + (kb - DIM) + c0);
                    v0 = p[0];
                    v1 = p[1];
                }
                *(int4*)&As[r][c0]     = v0;
                *(int4*)&As[r][c0 + 8] = v1;
            }
        }
        {
            const int dch = t >> 1;
            const int c0  = (t & 1) * 32;
            const float4* p = (const float4*)(W_c + (size_t)dch * (2 * DIM) + kb + c0);
            unsigned short* dp = &Bs[dch][c0];
            #pragma unroll
            for (int q = 0; q < 8; ++q) {
                const float4 v = p[q];
                *(ushort2*)&dp[q * 4]     = make_ushort2(f2bf(v.x), f2bf(v.y));
                *(ushort2*)&dp[q * 4 + 2] = make_ushort2(f2bf(v.z), f2bf(v.w));
            }
        }
        __syncthreads();
        #pragma unroll
        for (int s = 0; s < 2; ++s) {
            const int ko = s * 32 + (l >> 4) * 8;
            const short8 af = *(const short8*)&As[wv * 16 + (l & 15)][ko];
            #pragma unroll
            for (int nt = 0; nt < 8; ++nt) {
                const short8 bf = *(const short8*)&Bs[nt * 16 + (l & 15)][ko];
                acc[nt] = __builtin_amdgcn_mfma_f32_16x16x32_bf16(af, bf, acc[nt], 0, 0, 0);
            }
        }
    }

    const int col = l & 15;
    const int rq  = (l >> 4) * 4;
    #pragma unroll
    for (int nt = 0; nt < 8; ++nt) {
        const int dim = nt * 16 + col;
        const float bc = b_c[dim];
        #pragma unroll
        for (int r = 0; r < 4; ++r) {
            const int node = n0 + wv * 16 + rq + r;
            if (node < NN)
                out[(size_t)node * DIM + dim] = acc[nt][r] + bc;
        }
    }
}

// ---------------------------------------------------------------------------
extern "C" void kernel_launch(void* const* d_in, const int* in_sizes, int n_in,
                              void* d_out, int out_size, void* d_ws, size_t ws_size,
                              hipStream_t stream)
{
    const int*   node_type = (const int*)  d_in[0];
    const float* x_nodes   = (const float*)d_in[1];
    const int*   src       = (const int*)  d_in[2];
    const int*   dst       = (const int*)  d_in[3];
    const float* rbf       = (const float*)d_in[4];
    const float* dist      = (const float*)d_in[5];
    const float* emb       = (const float*)d_in[6];
    const float* W_e       = (const float*)d_in[7];
    const float* b_e       = (const float*)d_in[8];
    const float* W_c       = (const float*)d_in[9];
    const float* b_c       = (const float*)d_in[10];
    float* out = (float*)d_out;

    char* ws = (char*)d_ws;
    int*            deg      = (int*)(ws + OFF_DEG);
    int*            ovf_cnt  = (int*)(ws + OFF_OVFC);
    int*            eid      = (int*)(ws + OFF_EID);
    float*          ccb      = (float*)(ws + OFF_CCB);
    int*            taub     = (int*)(ws + OFF_TAUB);
    int*            ovf      = (int*)(ws + OFF_OVF);
    unsigned short* W_aug    = (unsigned short*)(ws + OFF_WAUG);
    unsigned short* emb_perm = (unsigned short*)(ws + OFF_EPERM);
    unsigned short* xi       = (unsigned short*)(ws + OFF_XI);

    hipMemsetAsync(deg, 0, (NN + 1) * sizeof(int), stream);

    prep_w<<<82, 256, 0, stream>>>(W_e, b_e, emb, W_aug, emb_perm);

    build_buckets<<<(NE + 255) / 256, 256, 0, stream>>>(
        dst, dist, src, node_type, deg, eid, ccb, taub, ovf, ovf_cnt);

    gather_fused<<<(NN + 3) / 4, 256, 0, stream>>>(
        rbf, deg, eid, ccb, taub, W_aug, emb_perm,
        ovf, ovf_cnt, dst, dist, src, node_type, xi);

    combine_mfma<<<(NN + 63) / 64, 256, 0, stream>>>(
        x_nodes, (const __hip_bfloat16*)xi, W_c, b_c, out);
}

// Round 4
// 367.291 us; speedup vs baseline: 1.2360x; 1.2360x over previous
//
#include <hip/hip_runtime.h>
#include <hip/hip_bf16.h>

// Problem constants (fixed by reference setup_inputs)
constexpr int NN   = 50000;    // nodes
constexpr int NE   = 600000;   // edges
constexpr int NRBF = 50;       // rbf features
constexpr int DIM  = 128;      // embedding dim
constexpr float CUT = 5.0f;
constexpr float PI_F = 3.14159265358979323846f;

constexpr int CAP = 32;        // bucket capacity (active degree ~Poisson(10); P(>32)~1e-9, ovf fallback)

// Workspace layout (byte offsets). Total 34.6 MB.
constexpr size_t OFF_DEG   = 0;                                // [NN] int
constexpr size_t OFF_OVFC  = (size_t)NN * 4;                   // [1] int (memset covers both)
constexpr size_t OFF_EID   = 200960;                           // [NN*CAP] int   (6.4 MB)
constexpr size_t OFF_CCB   = OFF_EID  + (size_t)NN * CAP * 4;  // [NN*CAP] float (6.4 MB)
constexpr size_t OFF_TAUB  = OFF_CCB  + (size_t)NN * CAP * 4;  // [NN*CAP] int   (6.4 MB)
constexpr size_t OFF_OVF   = OFF_TAUB + (size_t)NN * CAP * 4;  // [NE] int       (2.4 MB)
constexpr size_t OFF_WAUG  = OFF_OVF  + (size_t)NE * 4;        // [128*64] bf16 (16 KB)
constexpr size_t OFF_EPERM = OFF_WAUG + 128 * 64 * 2;          // [100*128] bf16 permuted (25.6 KB)
constexpr size_t OFF_XI    = OFF_EPERM + 100 * 128 * 2;        // [NN*128] bf16 normal order (12.8 MB)

// emb_perm PERMUTED layout: position p holds dim delta(p) = 16*(p&7) + (p>>3).
// Lane c's positions 8c..8c+7 <-> dims {16q + c} = exactly its MFMA-D column across nt.

typedef __attribute__((ext_vector_type(4))) float f32x4;
typedef __attribute__((ext_vector_type(8))) short short8;

__device__ __forceinline__ float bf2f(unsigned short u) {
    return __uint_as_float(((unsigned int)u) << 16);
}
__device__ __forceinline__ unsigned short f2bf(float f) {
    return __bfloat16_as_ushort(__float2bfloat16(f));
}

// ---------------------------------------------------------------------------
// Kernel 1 (MERGED prep_w + build_buckets): bucket active edges by dst; blocks
// whose global tids < 20992 additionally emit W_aug / emb_perm (independent
// outputs, consumed only by later kernels — kernel boundary is the fence).
// Saves one launch (probing the hidden ~250 us of non-edge-path time).
// ---------------------------------------------------------------------------
__global__ __launch_bounds__(256)
void bucket_prep(const int* __restrict__ dst, const float* __restrict__ dist,
                 const int* __restrict__ src, const int* __restrict__ node_type,
                 int* __restrict__ deg, int* __restrict__ eid,
                 float* __restrict__ ccb, int* __restrict__ taub,
                 int* __restrict__ ovf, int* __restrict__ ovf_cnt,
                 const float* __restrict__ W_e, const float* __restrict__ b_e,
                 const float* __restrict__ emb,
                 unsigned short* __restrict__ W_aug, unsigned short* __restrict__ emb_perm)
{
    const int e = blockIdx.x * 256 + threadIdx.x;

    if (e < NE) {
        const float dd = dist[e];
        if (dd < CUT) {
            const float w = 0.5f * (__cosf(dd * (PI_F / CUT)) + 1.0f);
            const int n = dst[e];
            const int pos = atomicAdd(&deg[n], 1);
            if (pos < CAP) {
                eid[n * CAP + pos]  = e;
                ccb[n * CAP + pos]  = w;
                taub[n * CAP + pos] = node_type[src[e]];
            } else {
                ovf[atomicAdd(ovf_cnt, 1)] = e;
            }
        }
    }

    // prep_w work, folded in (first 82 blocks' tids)
    if (e < 128 * 64) {
        const int d = e >> 6, k = e & 63;
        float v = 0.0f;
        if (k < NRBF)       v = W_e[d * NRBF + k];
        else if (k == NRBF) v = b_e[d];
        W_aug[e] = f2bf(v);
    } else if (e < 128 * 64 + 100 * 128) {
        const int i = e - 128 * 64;
        const int tau = i >> 7, p = i & 127;
        const int d = 16 * (p & 7) + (p >> 3);
        emb_perm[i] = f2bf(emb[tau * DIM + d]);
    }
}

// ---------------------------------------------------------------------------
// Kernel 2 (FUSED edge_msg + gather_sum, v2 — latency restructure).
//
// R3 post-mortem: v1 was correct but latency-serial (202 us @ 506 GB/s, all
// pipes idle): per wave, deg -> eid/ccb -> rbf -> taub -> emb_perm is a 4-5
// deep DEPENDENT chain for ~8 edges of work. v2 keeps the PROVEN per-node
// arithmetic bit-for-bit and restructures only latency:
//   (1) per-block LDS prestage of 8 nodes' bucket metadata (coalesced 1-KB
//       loads issued at block start) — removes 2 chain links;
//   (2) W_aug moved from 64 VGPRs to LDS (144-B padded rows: per-MFMA
//       ds_read_b128 spreads evenly over banks) — cuts VGPR residency and
//       amortizes the fragment fetch over 8 nodes;
//   (3) 2 nodes per wave, unrolled — two independent chains per wave so
//       node1's rbf gathers overlap node0's MFMA/epilogue.
// ---------------------------------------------------------------------------
__global__ __launch_bounds__(256)
void gather_fused(const float* __restrict__ rbf,
                  const int* __restrict__ deg, const int* __restrict__ eid,
                  const float* __restrict__ ccb, const int* __restrict__ taub,
                  const unsigned short* __restrict__ W_aug,
                  const unsigned short* __restrict__ emb_perm,
                  const int* __restrict__ ovf, const int* __restrict__ ovf_cnt,
                  const int* __restrict__ dst, const float* __restrict__ dist,
                  const int* __restrict__ src, const int* __restrict__ node_type,
                  unsigned short* __restrict__ xi)
{
    // W_aug tile: 128 rows x 72 shorts (144 B padded: row r starts at bank 4r%32,
    // so a per-MFMA b128 read (16 c-rows x 4 g-slots) spreads evenly: 8 lanes
    // per 4-bank group = the structural minimum, no 16-way pile-up).
    __shared__ __align__(16) unsigned short wlds[128 * 72];   // 18 KB
    __shared__ int   eid_s[256];
    __shared__ float ccb_s[256];
    __shared__ int   taub_s[256];
    __shared__ int   deg_s[8];

    const int t = threadIdx.x, l = t & 63;
    const int wv = t >> 6;
    const int c = l & 15, g = l >> 4;
    const int n0 = blockIdx.x * 8;

    // ---- block-level prestage (one sync total) ----
    {
        const int node_t = n0 + (t >> 5);          // 8 nodes x 32 slots
        if (node_t < NN) {
            const int gi = n0 * CAP + t;
            eid_s[t]  = eid[gi];
            ccb_s[t]  = ccb[gi];
            taub_s[t] = taub[gi];
        }
        if (t < 8) deg_s[t] = (n0 + t < NN) ? deg[n0 + t] : 0;
        #pragma unroll
        for (int i = 0; i < 4; ++i) {
            const int ch = i * 256 + t;            // 1024 x 16-B chunks
            const int row = ch >> 3, f = ch & 7;
            *(int4*)((char*)wlds + row * 144 + f * 16) = ((const int4*)W_aug)[ch];
        }
    }
    __syncthreads();

    #pragma unroll
    for (int ni = 0; ni < 2; ++ni) {
        const int nl = wv * 2 + ni;                // node slot within block (0..7)
        const int n  = n0 + nl;
        if (n >= NN) continue;

        const int dn   = deg_s[nl];
        const int degn = dn < CAP ? dn : CAP;
        const int mb   = nl * 32;

        float v[8] = {};

        for (int j0 = 0; j0 < degn; j0 += 16) {
            // This lane's A row: bucket slot j0+c from LDS.
            const int slot = j0 + c;
            int   ea  = 0;
            float ccl = 0.0f;
            if (slot < degn) {
                ea  = eid_s[mb + slot];
                ccl = ccb_s[mb + slot];
            }
            const float* rp = rbf + (size_t)ea * NRBF;    // ea=0 when inactive: safe

            const float2* rp2 = (const float2*)rp;
            const float2 r0 = rp2[4 * g];
            const float2 r1 = rp2[4 * g + 1];
            const float2 r2 = rp2[4 * g + 2];
            const float2 r3 = rp2[4 * g + 3];
            float2 q0 = make_float2(0.f, 0.f), q1 = q0, q2 = q0, q3 = q0;
            if (g < 2) {
                q0 = rp2[16 + 4 * g];
                q1 = rp2[17 + 4 * g];
                q2 = rp2[18 + 4 * g];
                q3 = rp2[19 + 4 * g];
            } else if (g == 2) {
                q0 = rp2[24];                             // k48,k49
            }

            short8 a0, a1;
            a0[0] = (short)f2bf(ccl * r0.x); a0[1] = (short)f2bf(ccl * r0.y);
            a0[2] = (short)f2bf(ccl * r1.x); a0[3] = (short)f2bf(ccl * r1.y);
            a0[4] = (short)f2bf(ccl * r2.x); a0[5] = (short)f2bf(ccl * r2.y);
            a0[6] = (short)f2bf(ccl * r3.x); a0[7] = (short)f2bf(ccl * r3.y);
            a1[0] = (short)f2bf(ccl * q0.x); a1[1] = (short)f2bf(ccl * q0.y);
            a1[2] = (short)f2bf(ccl * q1.x); a1[3] = (short)f2bf(ccl * q1.y);
            a1[4] = (short)f2bf(ccl * q2.x); a1[5] = (short)f2bf(ccl * q2.y);
            a1[6] = (short)f2bf(ccl * q3.x); a1[7] = (short)f2bf(ccl * q3.y);
            if (g == 2) {                                 // k50 = cc (b_e hook), k51+ = 0
                a1[2] = (short)f2bf(ccl);
                a1[3] = 0; a1[4] = 0; a1[5] = 0; a1[6] = 0; a1[7] = 0;
            }

            f32x4 acc[8] = {};
            // B fragment (nt,s) = wlds row nt*16+c, 16-B slot s*4+g
            // (shorts offset s*32+g*8 of the row == R3's register bfrag exactly).
            #pragma unroll
            for (int nt = 0; nt < 8; ++nt) {
                const short8 bf0 =
                    *(const short8*)((const char*)wlds + (nt * 16 + c) * 144 + g * 16);
                acc[nt] = __builtin_amdgcn_mfma_f32_16x16x32_bf16(a0, bf0, acc[nt], 0, 0, 0);
            }
            #pragma unroll
            for (int nt = 0; nt < 8; ++nt) {
                const short8 bf1 =
                    *(const short8*)((const char*)wlds + (nt * 16 + c) * 144 + (4 + g) * 16);
                acc[nt] = __builtin_amdgcn_mfma_f32_16x16x32_bf16(a1, bf1, acc[nt], 0, 0, 0);
            }

            // Accumulate: lane (c,g) owns dims 16nt+c of slots j0+4g+r.
            #pragma unroll
            for (int r = 0; r < 4; ++r) {
                const int jr = j0 + 4 * g + r;
                if (jr < degn) {
                    const int rw = taub_s[mb + jr];
                    const int4 em = *(const int4*)(emb_perm + rw * DIM + 8 * c);
                    const unsigned int* ep = (const unsigned int*)&em;
                    #pragma unroll
                    for (int q = 0; q < 4; ++q) {
                        const float m0 = bf2f((unsigned short)(ep[q] & 0xffff));
                        const float m1 = bf2f((unsigned short)(ep[q] >> 16));
                        // bf16-round each product: bit-identical to the msg path.
                        v[2 * q]     += bf2f(f2bf(acc[2 * q][r]     * m0));
                        v[2 * q + 1] += bf2f(f2bf(acc[2 * q + 1][r] * m1));
                    }
                }
            }
        }

        // Overflow fallback (deg > CAP): essentially never taken, kept for
        // correctness. Scalar recompute, g==0 lanes only (butterfly counts once).
        const int ocnt = ovf_cnt[0];
        for (int j = 0; j < ocnt; ++j) {
            const int e = ovf[j];
            if (dst[e] != n) continue;
            const float dd  = dist[e];
            const float ccl = 0.5f * (__cosf(dd * (PI_F / CUT)) + 1.0f);
            if (g == 0) {
                const int tau = node_type[src[e]];
                const float* rp = rbf + (size_t)e * NRBF;
                const float ccb16 = bf2f(f2bf(ccl));
                #pragma unroll
                for (int q = 0; q < 8; ++q) {
                    const int d = 16 * q + c;
                    float s = bf2f(W_aug[d * 64 + NRBF]) * ccb16;     // b_e * cc
                    for (int k = 0; k < NRBF; ++k)
                        s += bf2f(W_aug[d * 64 + k]) * bf2f(f2bf(ccl * rp[k]));
                    v[q] += bf2f(f2bf(s * bf2f(emb_perm[tau * DIM + 8 * c + q])));
                }
            }
        }

        #pragma unroll
        for (int q = 0; q < 8; ++q) {
            v[q] += __shfl_xor(v[q], 16);
            v[q] += __shfl_xor(v[q], 32);
        }

        // lane (c,g) holds dims {16q+c}; store dims 32g+c and 32g+16+c.
        float s0 = v[0], s1 = v[1];
        if (g == 1)      { s0 = v[2]; s1 = v[3]; }
        else if (g == 2) { s0 = v[4]; s1 = v[5]; }
        else if (g == 3) { s0 = v[6]; s1 = v[7]; }
        xi[(size_t)n * DIM + 32 * g + c]      = f2bf(s0);
        xi[(size_t)n * DIM + 32 * g + 16 + c] = f2bf(s1);
    }
}

// ---------------------------------------------------------------------------
// Kernel 3: out[n] = [x_nodes[n] | xi[n]] @ W_c^T + b_c  via bf16 MFMA.
// (unchanged — known good)
// ---------------------------------------------------------------------------
__global__ __launch_bounds__(256)
void combine_mfma(const float* __restrict__ x_nodes, const __hip_bfloat16* __restrict__ xi,
                  const float* __restrict__ W_c, const float* __restrict__ b_c,
                  float* __restrict__ out)
{
    __shared__ unsigned short As[64][72];
    __shared__ unsigned short Bs[128][72];

    const int t  = threadIdx.x;
    const int wv = t >> 6;
    const int l  = t & 63;
    const int n0 = blockIdx.x * 64;

    f32x4 acc[8] = {};

    for (int kc = 0; kc < 4; ++kc) {
        const int kb = kc * 64;
        if (kc) __syncthreads();
        {
            const int r  = t >> 2;
            const int c0 = (t & 3) * 16;
            const int n  = n0 + r;
            if (kc < 2) {
                float4 v[4];
                if (n < NN) {
                    const float4* p = (const float4*)(x_nodes + (size_t)n * DIM + kb + c0);
                    v[0] = p[0]; v[1] = p[1]; v[2] = p[2]; v[3] = p[3];
                } else {
                    v[0] = v[1] = v[2] = v[3] = make_float4(0.f, 0.f, 0.f, 0.f);
                }
                unsigned short* dp = &As[r][c0];
                #pragma unroll
                for (int q = 0; q < 4; ++q) {
                    *(ushort2*)&dp[q * 4]     = make_ushort2(f2bf(v[q].x), f2bf(v[q].y));
                    *(ushort2*)&dp[q * 4 + 2] = make_ushort2(f2bf(v[q].z), f2bf(v[q].w));
                }
            } else {
                int4 v0 = make_int4(0, 0, 0, 0), v1 = make_int4(0, 0, 0, 0);
                if (n < NN) {
                    const int4* p = (const int4*)(xi + (size_t)n * DIM + (kb - DIM) + c0);
                    v0 = p[0];
                    v1 = p[1];
                }
                *(int4*)&As[r][c0]     = v0;
                *(int4*)&As[r][c0 + 8] = v1;
            }
        }
        {
            const int dch = t >> 1;
            const int c0  = (t & 1) * 32;
            const float4* p = (const float4*)(W_c + (size_t)dch * (2 * DIM) + kb + c0);
            unsigned short* dp = &Bs[dch][c0];
            #pragma unroll
            for (int q = 0; q < 8; ++q) {
                const float4 v = p[q];
                *(ushort2*)&dp[q * 4]     = make_ushort2(f2bf(v.x), f2bf(v.y));
                *(ushort2*)&dp[q * 4 + 2] = make_ushort2(f2bf(v.z), f2bf(v.w));
            }
        }
        __syncthreads();
        #pragma unroll
        for (int s = 0; s < 2; ++s) {
            const int ko = s * 32 + (l >> 4) * 8;
            const short8 af = *(const short8*)&As[wv * 16 + (l & 15)][ko];
            #pragma unroll
            for (int nt = 0; nt < 8; ++nt) {
                const short8 bf = *(const short8*)&Bs[nt * 16 + (l & 15)][ko];
                acc[nt] = __builtin_amdgcn_mfma_f32_16x16x32_bf16(af, bf, acc[nt], 0, 0, 0);
            }
        }
    }

    const int col = l & 15;
    const int rq  = (l >> 4) * 4;
    #pragma unroll
    for (int nt = 0; nt < 8; ++nt) {
        const int dim = nt * 16 + col;
        const float bc = b_c[dim];
        #pragma unroll
        for (int r = 0; r < 4; ++r) {
            const int node = n0 + wv * 16 + rq + r;
            if (node < NN)
                out[(size_t)node * DIM + dim] = acc[nt][r] + bc;
        }
    }
}

// ---------------------------------------------------------------------------
extern "C" void kernel_launch(void* const* d_in, const int* in_sizes, int n_in,
                              void* d_out, int out_size, void* d_ws, size_t ws_size,
                              hipStream_t stream)
{
    const int*   node_type = (const int*)  d_in[0];
    const float* x_nodes   = (const float*)d_in[1];
    const int*   src       = (const int*)  d_in[2];
    const int*   dst       = (const int*)  d_in[3];
    const float* rbf       = (const float*)d_in[4];
    const float* dist      = (const float*)d_in[5];
    const float* emb       = (const float*)d_in[6];
    const float* W_e       = (const float*)d_in[7];
    const float* b_e       = (const float*)d_in[8];
    const float* W_c       = (const float*)d_in[9];
    const float* b_c       = (const float*)d_in[10];
    float* out = (float*)d_out;

    char* ws = (char*)d_ws;
    int*            deg      = (int*)(ws + OFF_DEG);
    int*            ovf_cnt  = (int*)(ws + OFF_OVFC);
    int*            eid      = (int*)(ws + OFF_EID);
    float*          ccb      = (float*)(ws + OFF_CCB);
    int*            taub     = (int*)(ws + OFF_TAUB);
    int*            ovf      = (int*)(ws + OFF_OVF);
    unsigned short* W_aug    = (unsigned short*)(ws + OFF_WAUG);
    unsigned short* emb_perm = (unsigned short*)(ws + OFF_EPERM);
    unsigned short* xi       = (unsigned short*)(ws + OFF_XI);

    hipMemsetAsync(deg, 0, (NN + 1) * sizeof(int), stream);

    bucket_prep<<<(NE + 255) / 256, 256, 0, stream>>>(
        dst, dist, src, node_type, deg, eid, ccb, taub, ovf, ovf_cnt,
        W_e, b_e, emb, W_aug, emb_perm);

    gather_fused<<<(NN + 7) / 8, 256, 0, stream>>>(
        rbf, deg, eid, ccb, taub, W_aug, emb_perm,
        ovf, ovf_cnt, dst, dist, src, node_type, xi);

    combine_mfma<<<(NN + 63) / 64, 256, 0, stream>>>(
        x_nodes, (const __hip_bfloat16*)xi, W_c, b_c, out);
}